// Round 1
// baseline (413.688 us; speedup 1.0000x reference)
//
#include <hip/hip_runtime.h>

// ---------------------------------------------------------------------------
// SparseMultiHeadAttention (windowed, W=4) forward on MI355X / gfx950
// outputs: [out (4,2048,1024) fp32] ++ [weights (4,16,2048,2048) fp32]
// Pipeline:
//   memset(weights)=0  (1.07 GB, dominates)
//   x   -> bf16                               (xconv_k)
//   Wq/Wk/Wv/Wo -> bf16 transposed [N][K]     (wconv_k)
//   Q,K,V = x@W + b  (bf16 MFMA, fp32 out)    (gemm_bf16_k<0>, grid.z=3)
//   banded softmax + PV in fp32               (attn_k)  writes band weights
//   out = attn@Wo + bo                        (gemm_bf16_k<1>)
// ---------------------------------------------------------------------------

typedef __attribute__((ext_vector_type(8))) short short8;
typedef __attribute__((ext_vector_type(4))) float f32x4;

#define B_    4
#define S_    2048
#define D_    1024
#define H_    16
#define HD_   64
#define WIN_  4
#define NROW  (B_ * S_)                         /* 8192 */
#define OUT0_ELEMS  ((size_t)B_ * S_ * D_)      /* 8388608 */
#define WEIGHT_ELEMS ((size_t)B_ * H_ * S_ * S_)/* 268435456 */

__device__ __forceinline__ unsigned short f2bf(float f) {
  unsigned int u = __float_as_uint(f);
  u += 0x7fffu + ((u >> 16) & 1u);              // round-to-nearest-even
  return (unsigned short)(u >> 16);
}

// ---------------- fp32 -> bf16 elementwise (x) ------------------------------
__global__ __launch_bounds__(256) void xconv_k(const float* __restrict__ x,
                                               unsigned short* __restrict__ o) {
  int i = blockIdx.x * 256 + threadIdx.x;       // one float4 per thread
  float4 f = reinterpret_cast<const float4*>(x)[i];
  ushort4 u;
  u.x = f2bf(f.x); u.y = f2bf(f.y); u.z = f2bf(f.z); u.w = f2bf(f.w);
  reinterpret_cast<ushort4*>(o)[i] = u;
}

// ---------------- fp32 [K][N] -> bf16 transposed [N][K] (4 weight mats) -----
__global__ __launch_bounds__(256) void wconv_k(const float* __restrict__ W0,
                                               const float* __restrict__ W1,
                                               const float* __restrict__ W2,
                                               const float* __restrict__ W3,
                                               unsigned short* __restrict__ out) {
  __shared__ float t[32][33];
  const float* Ws[4] = {W0, W1, W2, W3};
  const float* W = Ws[blockIdx.z];
  unsigned short* o = out + (size_t)blockIdx.z * D_ * D_;
  int tx = threadIdx.x;                         // 0..31
  int ty = threadIdx.y;                         // 0..7
  int n0 = blockIdx.x * 32, k0 = blockIdx.y * 32;
#pragma unroll
  for (int i = 0; i < 4; ++i)
    t[ty + 8 * i][tx] = W[(size_t)(k0 + ty + 8 * i) * D_ + (n0 + tx)];
  __syncthreads();
#pragma unroll
  for (int i = 0; i < 4; ++i)
    o[(size_t)(n0 + ty + 8 * i) * D_ + (k0 + tx)] = f2bf(t[tx][ty + 8 * i]);
}

// ---------------- bf16 MFMA GEMM, 128x128 tile, BK=32 (m97 structure) -------
// A [8192][1024] bf16 row-major; Bt [1024(N)][1024(K)] bf16 (pre-transposed W)
// MODE 0: scatter to per-head layout [B,H,S,Hd], pick z in {q,k,v}
// MODE 1: linear [row][col] into d_out
#define GLD16(g, l)                                                            \
  __builtin_amdgcn_global_load_lds(                                            \
      (const __attribute__((address_space(1))) unsigned int*)(g),              \
      (__attribute__((address_space(3))) unsigned int*)(l), 16, 0, 0)

template <int MODE>
__global__ __launch_bounds__(256) void gemm_bf16_k(
    const unsigned short* __restrict__ A, const unsigned short* __restrict__ WtBase,
    const float* __restrict__ b0, const float* __restrict__ b1,
    const float* __restrict__ b2, float* __restrict__ o0, float* __restrict__ o1,
    float* __restrict__ o2) {
  __shared__ unsigned short As[128 * 32];
  __shared__ unsigned short Bs[128 * 32];
  const int z = blockIdx.z;
  const unsigned short* Bt = WtBase + (size_t)z * (D_ * D_);
  const float* bias = (z == 0) ? b0 : (z == 1) ? b1 : b2;
  float* outp = (z == 0) ? o0 : (z == 1) ? o1 : o2;

  const int tid = threadIdx.x;
  const int lane = tid & 63;
  const int wid = tid >> 6;
  const int wm = wid >> 1, wn = wid & 1;
  const int row0 = blockIdx.x * 128;
  const int col0 = blockIdx.y * 128;

  f32x4 acc[4][4] = {};

  const int frow = lane & 15;          // fragment row (A) / col (B)
  const int koff = (lane >> 4) << 3;   // k-octet

  for (int kt = 0; kt < D_; kt += 32) {
#pragma unroll
    for (int i = 0; i < 2; ++i) {
      int c = tid + (i << 8);          // 0..511 chunk id (16B each)
      int r = c >> 2;
      int kk = (c & 3) << 3;
      GLD16(A + (size_t)(row0 + r) * D_ + kt + kk, (char*)As + c * 16);
      GLD16(Bt + (size_t)(col0 + r) * D_ + kt + kk, (char*)Bs + c * 16);
    }
    __syncthreads();
    short8 af[4], bfr[4];
#pragma unroll
    for (int mi = 0; mi < 4; ++mi)
      af[mi] = *reinterpret_cast<const short8*>(
          &As[(wm * 64 + mi * 16 + frow) * 32 + koff]);
#pragma unroll
    for (int ni = 0; ni < 4; ++ni)
      bfr[ni] = *reinterpret_cast<const short8*>(
          &Bs[(wn * 64 + ni * 16 + frow) * 32 + koff]);
#pragma unroll
    for (int mi = 0; mi < 4; ++mi)
#pragma unroll
      for (int ni = 0; ni < 4; ++ni)
        acc[mi][ni] = __builtin_amdgcn_mfma_f32_16x16x32_bf16(
            af[mi], bfr[ni], acc[mi][ni], 0, 0, 0);
    __syncthreads();
  }

#pragma unroll
  for (int mi = 0; mi < 4; ++mi) {
#pragma unroll
    for (int ni = 0; ni < 4; ++ni) {
#pragma unroll
      for (int r = 0; r < 4; ++r) {
        int gr = row0 + wm * 64 + mi * 16 + ((lane >> 4) << 2) + r;
        int gc = col0 + wn * 64 + ni * 16 + (lane & 15);
        float val = acc[mi][ni][r] + bias[gc];
        if (MODE == 0) {
          int b = gr >> 11, s = gr & (S_ - 1);
          int h = gc >> 6, hd = gc & 63;
          outp[(((size_t)(b * H_ + h) * S_ + s) << 6) + hd] = val;
        } else {
          outp[(size_t)gr * D_ + gc] = val;
        }
      }
    }
  }
}

// ---------------- banded attention: one wave per (b,h,q) row ---------------
__global__ __launch_bounds__(256) void attn_k(const float* __restrict__ Q,
                                              const float* __restrict__ K,
                                              const float* __restrict__ V,
                                              float* __restrict__ wout,
                                              unsigned short* __restrict__ attn) {
  int lane = threadIdx.x & 63;
  int wid = threadIdx.x >> 6;
  int row = blockIdx.x * 4 + wid;      // bh*2048 + s, 0..131071
  int s = row & (S_ - 1);
  int bh = row >> 11;                  // b*16 + h
  int b = bh >> 4, h = bh & 15;
  float qd = Q[(size_t)row * HD_ + lane];
  const float* Kb = K + (size_t)bh * S_ * HD_;
  const float* Vb = V + (size_t)bh * S_ * HD_;

  float sc[9];
#pragma unroll
  for (int j = 0; j < 9; ++j) {
    int ks = s - WIN_ + j;
    bool ok = (ks >= 0) && (ks < S_);
    float v = ok ? qd * Kb[(size_t)ks * HD_ + lane] : 0.f;
#pragma unroll
    for (int off = 32; off > 0; off >>= 1) v += __shfl_xor(v, off, 64);
    sc[j] = ok ? v * 0.125f : -INFINITY;   // 1/sqrt(64)
  }
  float m = sc[0];
#pragma unroll
  for (int j = 1; j < 9; ++j) m = fmaxf(m, sc[j]);
  float w[9];
  float sum = 0.f;
#pragma unroll
  for (int j = 0; j < 9; ++j) { w[j] = __expf(sc[j] - m); sum += w[j]; }
  float inv = 1.f / sum;
  float o = 0.f;
#pragma unroll
  for (int j = 0; j < 9; ++j) {
    int ks = s - WIN_ + j;
    if (ks >= 0 && ks < S_) o += (w[j] * inv) * Vb[(size_t)ks * HD_ + lane];
  }
  if (lane < 9) {
    int ks = s - WIN_ + lane;
    if (ks >= 0 && ks < S_) wout[(size_t)row * S_ + ks] = w[lane] * inv;
  }
  attn[((size_t)(b * S_ + s)) * D_ + h * HD_ + lane] = f2bf(o);
}

// ---------------------------------------------------------------------------
extern "C" void kernel_launch(void* const* d_in, const int* in_sizes, int n_in,
                              void* d_out, int out_size, void* d_ws,
                              size_t ws_size, hipStream_t stream) {
  const float* x = (const float*)d_in[0];
  const float* Wq = (const float*)d_in[1];
  const float* bq = (const float*)d_in[2];
  const float* Wk = (const float*)d_in[3];
  const float* bk = (const float*)d_in[4];
  const float* Wv = (const float*)d_in[5];
  const float* bv = (const float*)d_in[6];
  const float* Wo = (const float*)d_in[7];
  const float* bo = (const float*)d_in[8];
  float* out = (float*)d_out;
  float* wout = out + OUT0_ELEMS;

  char* ws = (char*)d_ws;
  unsigned short* x_bf = (unsigned short*)(ws);               // 16 MB
  unsigned short* Wt = (unsigned short*)(ws + (16ull << 20)); //  8 MB (4 mats)
  float* Qf = (float*)(ws + (24ull << 20));                   // 32 MB
  float* Kf = (float*)(ws + (56ull << 20));                   // 32 MB
  float* Vf = (float*)(ws + (88ull << 20));                   // 32 MB
  unsigned short* attn = (unsigned short*)(ws + (120ull << 20)); // 16 MB

  // zero the dense weights output (band entries overwritten by attn_k)
  hipMemsetAsync(wout, 0, WEIGHT_ELEMS * sizeof(float), stream);

  xconv_k<<<NROW * D_ / 1024, 256, 0, stream>>>(x, x_bf);
  wconv_k<<<dim3(32, 32, 4), dim3(32, 8), 0, stream>>>(Wq, Wk, Wv, Wo, Wt);
  gemm_bf16_k<0><<<dim3(64, 8, 3), 256, 0, stream>>>(x_bf, Wt, bq, bk, bv, Qf,
                                                     Kf, Vf);
  attn_k<<<(B_ * H_ * S_) / 4, 256, 0, stream>>>(Qf, Kf, Vf, wout, attn);
  gemm_bf16_k<1><<<dim3(64, 8, 1), 256, 0, stream>>>(
      attn, Wt + (size_t)3 * D_ * D_, bo, bo, bo, out, out, out);
}

// Round 3
// 301.848 us; speedup vs baseline: 1.3705x; 1.3705x over previous
//
#include <hip/hip_runtime.h>

// ---------------------------------------------------------------------------
// SparseMultiHeadAttention (windowed, W=4) forward on MI355X / gfx950
// outputs: [out (4,2048,1024) fp32] ++ [weights (4,16,2048,2048) fp32]
// Pipeline (R3: R2 with ext_vector f32x4 for nontemporal stores):
//   x   -> bf16                               (xconv_k)
//   Wq/Wk/Wv/Wo -> bf16 transposed [N][K]     (wconv_k)
//   Q,K,V = x@W + b  (bf16 MFMA, fp32 out)    (gemm_bf16_k<0>, grid.z=3)
//   banded softmax + PV + FULL weights-row
//   write (zeros + band, NT f32x4)            (attn_k)
//   out = attn@Wo + bo                        (gemm_bf16_k<1>)
// ---------------------------------------------------------------------------

typedef __attribute__((ext_vector_type(8))) short short8;
typedef __attribute__((ext_vector_type(4))) float f32x4;

#define B_    4
#define S_    2048
#define D_    1024
#define H_    16
#define HD_   64
#define WIN_  4
#define NROW  (B_ * S_)                         /* 8192 */
#define OUT0_ELEMS  ((size_t)B_ * S_ * D_)      /* 8388608 */
#define WEIGHT_ELEMS ((size_t)B_ * H_ * S_ * S_)/* 268435456 */

__device__ __forceinline__ unsigned short f2bf(float f) {
  unsigned int u = __float_as_uint(f);
  u += 0x7fffu + ((u >> 16) & 1u);              // round-to-nearest-even
  return (unsigned short)(u >> 16);
}

// ---------------- fp32 -> bf16 elementwise (x) ------------------------------
__global__ __launch_bounds__(256) void xconv_k(const float* __restrict__ x,
                                               unsigned short* __restrict__ o) {
  int i = blockIdx.x * 256 + threadIdx.x;       // one float4 per thread
  float4 f = reinterpret_cast<const float4*>(x)[i];
  ushort4 u;
  u.x = f2bf(f.x); u.y = f2bf(f.y); u.z = f2bf(f.z); u.w = f2bf(f.w);
  reinterpret_cast<ushort4*>(o)[i] = u;
}

// ---------------- fp32 [K][N] -> bf16 transposed [N][K] (4 weight mats) -----
__global__ __launch_bounds__(256) void wconv_k(const float* __restrict__ W0,
                                               const float* __restrict__ W1,
                                               const float* __restrict__ W2,
                                               const float* __restrict__ W3,
                                               unsigned short* __restrict__ out) {
  __shared__ float t[32][33];
  const float* Ws[4] = {W0, W1, W2, W3};
  const float* W = Ws[blockIdx.z];
  unsigned short* o = out + (size_t)blockIdx.z * D_ * D_;
  int tx = threadIdx.x;                         // 0..31
  int ty = threadIdx.y;                         // 0..7
  int n0 = blockIdx.x * 32, k0 = blockIdx.y * 32;
#pragma unroll
  for (int i = 0; i < 4; ++i)
    t[ty + 8 * i][tx] = W[(size_t)(k0 + ty + 8 * i) * D_ + (n0 + tx)];
  __syncthreads();
#pragma unroll
  for (int i = 0; i < 4; ++i)
    o[(size_t)(n0 + ty + 8 * i) * D_ + (k0 + tx)] = f2bf(t[tx][ty + 8 * i]);
}

// ---------------- bf16 MFMA GEMM, 128x128 tile, BK=32 (m97 structure) -------
// A [8192][1024] bf16 row-major; Bt [1024(N)][1024(K)] bf16 (pre-transposed W)
// MODE 0: scatter to per-head layout [B,H,S,Hd], pick z in {q,k,v}
// MODE 1: linear [row][col] into d_out
#define GLD16(g, l)                                                            \
  __builtin_amdgcn_global_load_lds(                                            \
      (const __attribute__((address_space(1))) unsigned int*)(g),              \
      (__attribute__((address_space(3))) unsigned int*)(l), 16, 0, 0)

template <int MODE>
__global__ __launch_bounds__(256) void gemm_bf16_k(
    const unsigned short* __restrict__ A, const unsigned short* __restrict__ WtBase,
    const float* __restrict__ b0, const float* __restrict__ b1,
    const float* __restrict__ b2, float* __restrict__ o0, float* __restrict__ o1,
    float* __restrict__ o2) {
  __shared__ unsigned short As[128 * 32];
  __shared__ unsigned short Bs[128 * 32];
  const int z = blockIdx.z;
  const unsigned short* Bt = WtBase + (size_t)z * (D_ * D_);
  const float* bias = (z == 0) ? b0 : (z == 1) ? b1 : b2;
  float* outp = (z == 0) ? o0 : (z == 1) ? o1 : o2;

  const int tid = threadIdx.x;
  const int lane = tid & 63;
  const int wid = tid >> 6;
  const int wm = wid >> 1, wn = wid & 1;
  const int row0 = blockIdx.x * 128;
  const int col0 = blockIdx.y * 128;

  f32x4 acc[4][4] = {};

  const int frow = lane & 15;          // fragment row (A) / col (B)
  const int koff = (lane >> 4) << 3;   // k-octet

  for (int kt = 0; kt < D_; kt += 32) {
#pragma unroll
    for (int i = 0; i < 2; ++i) {
      int c = tid + (i << 8);          // 0..511 chunk id (16B each)
      int r = c >> 2;
      int kk = (c & 3) << 3;
      GLD16(A + (size_t)(row0 + r) * D_ + kt + kk, (char*)As + c * 16);
      GLD16(Bt + (size_t)(col0 + r) * D_ + kt + kk, (char*)Bs + c * 16);
    }
    __syncthreads();
    short8 af[4], bfr[4];
#pragma unroll
    for (int mi = 0; mi < 4; ++mi)
      af[mi] = *reinterpret_cast<const short8*>(
          &As[(wm * 64 + mi * 16 + frow) * 32 + koff]);
#pragma unroll
    for (int ni = 0; ni < 4; ++ni)
      bfr[ni] = *reinterpret_cast<const short8*>(
          &Bs[(wn * 64 + ni * 16 + frow) * 32 + koff]);
#pragma unroll
    for (int mi = 0; mi < 4; ++mi)
#pragma unroll
      for (int ni = 0; ni < 4; ++ni)
        acc[mi][ni] = __builtin_amdgcn_mfma_f32_16x16x32_bf16(
            af[mi], bfr[ni], acc[mi][ni], 0, 0, 0);
    __syncthreads();
  }

#pragma unroll
  for (int mi = 0; mi < 4; ++mi) {
#pragma unroll
    for (int ni = 0; ni < 4; ++ni) {
#pragma unroll
      for (int r = 0; r < 4; ++r) {
        int gr = row0 + wm * 64 + mi * 16 + ((lane >> 4) << 2) + r;
        int gc = col0 + wn * 64 + ni * 16 + (lane & 15);
        float val = acc[mi][ni][r] + bias[gc];
        if (MODE == 0) {
          int b = gr >> 11, s = gr & (S_ - 1);
          int h = gc >> 6, hd = gc & 63;
          outp[(((size_t)(b * H_ + h) * S_ + s) << 6) + hd] = val;
        } else {
          outp[(size_t)gr * D_ + gc] = val;
        }
      }
    }
  }
}

// ---------------- banded attention + full weights-row write ----------------
// one wave per (b,h,q) row; 64 lanes write the entire 2048-float row
// (zeros + 9 band values) as 512 coalesced NT f32x4 stores.
__global__ __launch_bounds__(256) void attn_k(const float* __restrict__ Q,
                                              const float* __restrict__ K,
                                              const float* __restrict__ V,
                                              float* __restrict__ wout,
                                              unsigned short* __restrict__ attn) {
  int lane = threadIdx.x & 63;
  int wid = threadIdx.x >> 6;
  int row = blockIdx.x * 4 + wid;      // bh*2048 + s, 0..131071
  int s = row & (S_ - 1);
  int bh = row >> 11;                  // b*16 + h
  int b = bh >> 4, h = bh & 15;
  float qd = Q[(size_t)row * HD_ + lane];
  const float* Kb = K + (size_t)bh * S_ * HD_;
  const float* Vb = V + (size_t)bh * S_ * HD_;

  float sc[9];
#pragma unroll
  for (int j = 0; j < 9; ++j) {
    int ks = s - WIN_ + j;
    bool ok = (ks >= 0) && (ks < S_);
    float v = ok ? qd * Kb[(size_t)ks * HD_ + lane] : 0.f;
#pragma unroll
    for (int off = 32; off > 0; off >>= 1) v += __shfl_xor(v, off, 64);
    sc[j] = ok ? v * 0.125f : -INFINITY;   // 1/sqrt(64)
  }
  float m = sc[0];
#pragma unroll
  for (int j = 1; j < 9; ++j) m = fmaxf(m, sc[j]);
  float w[9];
  float sum = 0.f;
#pragma unroll
  for (int j = 0; j < 9; ++j) { w[j] = __expf(sc[j] - m); sum += w[j]; }
  float inv = 1.f / sum;
#pragma unroll
  for (int j = 0; j < 9; ++j) w[j] *= inv;   // normalized weights (wave-uniform)

  float o = 0.f;
#pragma unroll
  for (int j = 0; j < 9; ++j) {
    int ks = s - WIN_ + j;
    if (ks >= 0 && ks < S_) o += w[j] * Vb[(size_t)ks * HD_ + lane];
  }
  attn[((size_t)(b * S_ + s)) * D_ + h * HD_ + lane] = f2bf(o);

  // ---- full weights row: 8 NT f32x4 per lane, band select-merged ----
  f32x4* rowp = reinterpret_cast<f32x4*>(wout + (size_t)row * S_);
  const int lo = s - WIN_;             // first band col (may be <0)
  const int hi = s + WIN_;             // last band col (may be >=S_)
#pragma unroll
  for (int i = 0; i < 8; ++i) {
    int f = lane + (i << 6);           // f32x4 chunk 0..511
    int c0 = f << 2;                   // first col of chunk
    f32x4 v4 = {0.f, 0.f, 0.f, 0.f};
    if (c0 + 3 >= lo && c0 <= hi) {    // chunk overlaps band (≤3 lanes)
#pragma unroll
      for (int e = 0; e < 4; ++e) {
        int d = c0 + e - lo;           // band index if in [0,8]
        float val = 0.f;
#pragma unroll
        for (int j = 0; j < 9; ++j)
          if (d == j) val = w[j];      // static-index select chain
        v4[e] = val;
      }
    }
    __builtin_nontemporal_store(v4, rowp + f);
  }
}

// ---------------------------------------------------------------------------
extern "C" void kernel_launch(void* const* d_in, const int* in_sizes, int n_in,
                              void* d_out, int out_size, void* d_ws,
                              size_t ws_size, hipStream_t stream) {
  const float* x = (const float*)d_in[0];
  const float* Wq = (const float*)d_in[1];
  const float* bq = (const float*)d_in[2];
  const float* Wk = (const float*)d_in[3];
  const float* bk = (const float*)d_in[4];
  const float* Wv = (const float*)d_in[5];
  const float* bv = (const float*)d_in[6];
  const float* Wo = (const float*)d_in[7];
  const float* bo = (const float*)d_in[8];
  float* out = (float*)d_out;
  float* wout = out + OUT0_ELEMS;

  char* ws = (char*)d_ws;
  unsigned short* x_bf = (unsigned short*)(ws);               // 16 MB
  unsigned short* Wt = (unsigned short*)(ws + (16ull << 20)); //  8 MB (4 mats)
  float* Qf = (float*)(ws + (24ull << 20));                   // 32 MB
  float* Kf = (float*)(ws + (56ull << 20));                   // 32 MB
  float* Vf = (float*)(ws + (88ull << 20));                   // 32 MB
  unsigned short* attn = (unsigned short*)(ws + (120ull << 20)); // 16 MB

  xconv_k<<<NROW * D_ / 1024, 256, 0, stream>>>(x, x_bf);
  wconv_k<<<dim3(32, 32, 4), dim3(32, 8), 0, stream>>>(Wq, Wk, Wv, Wo, Wt);
  gemm_bf16_k<0><<<dim3(64, 8, 3), 256, 0, stream>>>(x_bf, Wt, bq, bk, bv, Qf,
                                                     Kf, Vf);
  attn_k<<<(B_ * H_ * S_) / 4, 256, 0, stream>>>(Qf, Kf, Vf, wout, attn);
  gemm_bf16_k<1><<<dim3(64, 8, 1), 256, 0, stream>>>(
      attn, Wt + (size_t)3 * D_ * D_, bo, bo, bo, out, out, out);
}